// Round 3
// baseline (328.955 us; speedup 1.0000x reference)
//
#include <hip/hip_runtime.h>
#include <math.h>

// B=4, H=256, W=256, 100 iters. Closed-form update (3-pt GH quadrature is
// exact for these degree<=4 integrands; log/NDC terms cancel):
//   dmu  = 2*uw1*mu + uw2*y + sum_edges ew*mu_nb
//   dsg  = 2*uw1*sg + sum_edges ew*rou_edge*sg_nb
//   drou = ew*sg_self*sg_nb        (per owned edge)
// Temporal blocking: T=10 iters/launch, 256 blocks (1/CU), double-buffered
// LDS, 1 barrier/iter.
// Round 11: 3x3 pixel patch per thread. Iteration phase is DS-throughput
// bound (r10 post-mortem: -16% wave-work -> -14us). A 1-wide row strip costs
// 11 DS / 3 px = 3.67/px; a 3x3 patch shares lf/rt across rows and up/dn
// across cols: 12 reads + 9 writes / 9 px = 2.33/px (-36%). Stride-3 float4
// LDS access is bank-conflict-free (quad-starts 12k mod 32 cover all 8
// quads). Tile 54x54 (halo 11 both dims, 1 spare garbage ring), 18x18=324
// active threads of 384 (6 waves), shrinking gate on BOTH rg and cg.
// st+v+k1 = 108 VGPR + temps fits 256 cap at launch_bounds(384,2).
#define NPIX  262144
#define NEDGE 524288
#define ITERS 100
#define T     10
#define TILE  54            // 32 + 11 + 11 (1 spare garbage ring)
#define TS    55            // padded LDS row stride (float4 units)
#define PR    3             // patch rows per thread
#define PC    3             // patch cols per thread
#define NRG   18            // 18*3 = 54 exact
#define NCG   18
#define ACTIVE (NRG*NCG)    // 324 active threads of 384
#define HALO  11
#define NTHR  384

__device__ __forceinline__ float clampf(float x, float lo, float hi) {
    return fminf(fmaxf(x, lo), hi);
}

// State float4 {mu, sigma, rou0(down-edge), rou1(right-edge)}.
// c1 = {2*uw1, uw2*y, ew0, ew1}.
__global__ __launch_bounds__(NTHR, 2) void tile_kernel(
    const float4* __restrict__ stI, const float4* __restrict__ vI,
    float4* __restrict__ stO, float4* __restrict__ vO,
    const float4* __restrict__ c1,
    float* __restrict__ mu_out,   // non-null on last launch (st/v not stored)
    int first)                    // launch 0: v := 0, vI not read
{
    __shared__ float4 buf[2][TILE*TS];   // 95.0 KB

    int tid = threadIdx.x;
    int rg  = tid / NCG;
    int cg  = tid - rg*NCG;
    bool act = (tid < ACTIVE);
    int bz = blockIdx.z;
    int h0 = blockIdx.y * 32;
    int w0 = blockIdx.x * 32;
    int r0 = PR*rg, c0 = PC*cg;

    float4 st[PR][PC], v[PR][PC], k1[PR][PC];
    float k2x[PC];   // ew0 of up-neighbor for top-row px
    float k2y[PR];   // ew1 of left-neighbor for left-col px
    int hh[PR], ww[PC];

    // ---- load tile: st -> LDS buf0 + regs; c1 -> regs; ew pair -> buf1 ----
    float2* ews = (float2*)&buf[1][0];   // staging view, overwritten by iter 0
    if (act) {
#pragma unroll
        for (int i = 0; i < PR; ++i) hh[i] = (h0 + r0 + i - HALO) & 255;
#pragma unroll
        for (int j = 0; j < PC; ++j) ww[j] = (w0 + c0 + j - HALO) & 255;
#pragma unroll
        for (int i = 0; i < PR; ++i) {
#pragma unroll
            for (int j = 0; j < PC; ++j) {
                int g = (bz << 16) | (hh[i] << 8) | ww[j];
                float4 s = stI[g];
                st[i][j] = s;
                buf[0][(r0+i)*TS + c0+j] = s;
                float4 K = c1[g];
                k1[i][j] = K;
                ews[(r0+i)*TS + c0+j] = make_float2(K.z, K.w);
                v[i][j] = first ? make_float4(0.f,0.f,0.f,0.f) : vI[g];
            }
        }
    }
    __syncthreads();

    // gather boundary neighbor ew (interior of patch comes from k1 regs).
    // Clamped at tile edge -> finite garbage; edge px are garbage-region.
    if (act) {
        int ru = (r0 == 0) ? 0 : r0-1;
        int cl = (c0 == 0) ? 0 : c0-1;
#pragma unroll
        for (int j = 0; j < PC; ++j) k2x[j] = ews[ru*TS + c0+j].x;
#pragma unroll
        for (int i = 0; i < PR; ++i) k2y[i] = ews[(r0+i)*TS + cl].y;
    }
    __syncthreads();   // k2 reads done before iter-0 writes buf1

    // ---- T fused Jacobi iterations, one barrier each, shrinking 2D gate ----
    for (int s = 0; s < T; ++s) {
        const float4* __restrict__ cur = buf[s & 1];
        float4*       __restrict__ nxt = buf[(s & 1) ^ 1];
        int gLo = (s + 2) / 3;      // group gate: rows/cols [s+2, 51-s]
        int gHi = (51 - s) / 3;
        if (act && rg >= gLo && rg <= gHi && cg >= gLo && cg <= gHi) {
            int rup = (rg == 0)     ? r0   : r0-1;
            int rdn = (rg == NRG-1) ? r0+2 : r0+3;
            int clf = (cg == 0)     ? c0   : c0-1;
            int crt = (cg == NCG-1) ? c0+2 : c0+3;
            float4 up[PC], dn[PC], lf[PR], rt[PR];
#pragma unroll
            for (int j = 0; j < PC; ++j) {
                up[j] = cur[rup*TS + c0+j];
                dn[j] = cur[rdn*TS + c0+j];
            }
#pragma unroll
            for (int i = 0; i < PR; ++i) {
                lf[i] = cur[(r0+i)*TS + clf];
                rt[i] = cur[(r0+i)*TS + crt];
            }
            float4 ns[PR][PC];
#pragma unroll
            for (int i = 0; i < PR; ++i) {
#pragma unroll
                for (int j = 0; j < PC; ++j) {
                    float4 U = (i == 0)    ? up[j] : st[i-1][j];
                    float4 D = (i == PR-1) ? dn[j] : st[i+1][j];
                    float4 L = (j == 0)    ? lf[i] : st[i][j-1];
                    float4 R = (j == PC-1) ? rt[i] : st[i][j+1];
                    float4 S = st[i][j];
                    float4 K = k1[i][j];
                    float K2x = (i == 0) ? k2x[j] : k1[i-1][j].z;
                    float K2y = (j == 0) ? k2y[i] : k1[i][j-1].w;
                    float dmu = K.x*S.x + K.y + K.z*D.x + K.w*R.x
                              + K2x*U.x + K2y*L.x;
                    float dsg = K.x*S.y + K.z*S.z*D.y + K.w*S.w*R.y
                              + K2x*U.z*U.y + K2y*L.w*L.y;
                    float dr0 = K.z*S.y*D.y;
                    float dr1 = K.w*S.y*R.y;
                    float4 V = v[i][j];
                    V.x = 0.7f*V.x + 0.01f*dmu;
                    V.y = 0.7f*V.y + 0.01f*dsg;
                    V.z = 0.7f*V.z + 0.01f*dr0;
                    V.w = 0.7f*V.w + 0.01f*dr1;
                    v[i][j] = V;
                    float4 o;
                    o.x = clampf(S.x + V.x, 0.f, 63.f);
                    o.y = clampf(S.y + V.y, 0.001f, 50.f);
                    o.z = clampf(S.z + V.z, -0.99f, 0.99f);
                    o.w = clampf(S.w + V.w, -0.99f, 0.99f);
                    ns[i][j] = o;
                }
            }
#pragma unroll
            for (int i = 0; i < PR; ++i) {
#pragma unroll
                for (int j = 0; j < PC; ++j) {
                    st[i][j] = ns[i][j];
                    nxt[(r0+i)*TS + c0+j] = ns[i][j];
                }
            }
        }
        __syncthreads();   // all reads of cur done AND nxt fully written
    }

    // ---- store interior (rows/cols [HALO, HALO+32)) ----
    if (act) {
#pragma unroll
        for (int i = 0; i < PR; ++i) {
#pragma unroll
            for (int j = 0; j < PC; ++j) {
                int r = r0+i, c = c0+j;
                if (r >= HALO && r < HALO+32 && c >= HALO && c < HALO+32) {
                    int g = (bz << 16) | (hh[i] << 8) | ww[j];
                    if (mu_out) {
                        mu_out[g] = st[i][j].x;   // final launch: only mu
                    } else {
                        stO[g] = st[i][j];
                        vO[g]  = v[i][j];
                    }
                }
            }
        }
    }
}

// ---- global max(edge_weight); gmax pre-zeroed via hipMemsetAsync ----
// (0u is the order-preserving encoding of the most-negative float)
__global__ void reduce_max_kernel(const float* __restrict__ ew, unsigned int* gmax) {
    int i = blockIdx.x*blockDim.x + threadIdx.x;
    float m = -INFINITY;
    for (; i < NEDGE; i += gridDim.x*blockDim.x) m = fmaxf(m, ew[i]);
#pragma unroll
    for (int off = 32; off > 0; off >>= 1)
        m = fmaxf(m, __shfl_down(m, off, 64));
    if ((threadIdx.x & 63) == 0) {
        unsigned u = __float_as_uint(m);
        unsigned key = (u & 0x80000000u) ? ~u : (u | 0x80000000u);
        atomicMax(gmax, key);
    }
}

// init state + invariant coefficient plane (no v plane, no c2 plane)
__global__ __launch_bounds__(256) void init_state_kernel(
    const float*  __restrict__ y,
    const float2* __restrict__ ew,
    const float2* __restrict__ uw,
    const unsigned int* __restrict__ gmax_enc,
    float4* stA, float4* c1)
{
    int idx = blockIdx.x*256 + threadIdx.x;

    unsigned key = *gmax_enc;
    unsigned u = (key & 0x80000000u) ? (key ^ 0x80000000u) : ~key;
    float gmax = __uint_as_float(u);
    float inv_denom = 1.f / (gmax*1.01f + 1.f);   // one-time, IEEE div fine

    float2 e   = ew[idx];
    float2 uwv = uw[idx];
    float  yv  = y[idx];
    float4 st;
    st.x = yv;
    st.y = 1.f;
    st.z = e.x * inv_denom;
    st.w = e.y * inv_denom;
    stA[idx] = st;
    c1[idx]  = make_float4(2.f*uwv.x, uwv.y*yv, e.x, e.y);
}

extern "C" void kernel_launch(void* const* d_in, const int* in_sizes, int n_in,
                              void* d_out, int out_size, void* d_ws, size_t ws_size,
                              hipStream_t stream) {
    const float* y  = (const float*)d_in[0];
    const float* ew = (const float*)d_in[1];
    const float* uw = (const float*)d_in[2];
    float* out = (float*)d_out;
    const int N = NPIX;

    // workspace: stA, stB, vA, vB, c1 (float4 planes) + 1 uint (~21 MB)
    float4* stA = (float4*)d_ws;
    float4* stB = stA + N;
    float4* vA  = stB + N;
    float4* vB  = vA + N;
    float4* c1  = vB + N;
    unsigned int* gmax = (unsigned int*)(c1 + N);

    hipMemsetAsync(gmax, 0, sizeof(unsigned int), stream);
    hipLaunchKernelGGL(reduce_max_kernel, dim3(512), dim3(256), 0, stream, ew, gmax);
    hipLaunchKernelGGL(init_state_kernel, dim3(N/256), dim3(256), 0, stream,
                       y, (const float2*)ew, (const float2*)uw, gmax,
                       stA, c1);

    float4 *stI = stA, *stO = stB, *vI = vA, *vO = vB;
    const int NLAUNCH = ITERS / T;   // 10
    for (int l = 0; l < NLAUNCH; ++l) {
        float* mo = (l == NLAUNCH-1) ? out : nullptr;
        hipLaunchKernelGGL(tile_kernel, dim3(8, 8, 4), dim3(NTHR), 0, stream,
                           stI, vI, stO, vO, c1, mo, (l == 0) ? 1 : 0);
        float4* t;
        t = stI; stI = stO; stO = t;
        t = vI;  vI  = vO;  vO  = t;
    }
}

// Round 4
// 259.662 us; speedup vs baseline: 1.2669x; 1.2669x over previous
//
#include <hip/hip_runtime.h>
#include <math.h>

// B=4, H=256, W=256, 100 iters. Closed-form update (3-pt GH quadrature is
// exact for these degree<=4 integrands; log/NDC terms cancel):
//   dmu  = 2*uw1*mu + uw2*y + sum_edges ew*mu_nb
//   dsg  = 2*uw1*sg + sum_edges ew*rou_edge*sg_nb
//   drou = ew*sg_self*sg_nb        (per owned edge)
// Temporal blocking, double-buffered LDS, 1 barrier/iter, shrinking gate.
// Round 12: revert r11's 3x3 patch (6 waves/CU exposed DS latency + likely
// spill -> 329us). Back to r10 strip structure, but T=10 -> T=16:
// per-launch fixed overhead (~11us: launch gap + barrier drain + prologue
// latency) amortizes 1/T while halo compute grows (32+2T)^2 -> optimum ~16.
// Tile 70 rows x 64 cols: TILE_C=64 makes each wave exactly one rowgroup
// (zero gate divergence; banks 4c mod 32 = all 8 quads = conflict-free),
// 896 threads ALL active (14 waves), RPT=5 strips (17 DS / 5 px), LDS
// 2*70*65*16 = 145.6 KB. Runtime Tl per launch: 6x16 + 1x4 = 100 iters,
// 7 launches vs 10. Gate rows [18-Tl+s, 47+Tl-s]; stored rows 17..48 =
// rowgroups 3..9 stay inside the gate at every step for both Tl values.
#define NPIX  262144
#define NEDGE 524288
#define ITERS 100
#define TILE_R 70           // 32 + 2*17 + 4 spare
#define TILE_C 64           // 32 + 2*16
#define TS     65           // padded LDS row stride (float4 units)
#define RPT    5            // rows per thread
#define NRG    14           // 14*5 = 70 exact
#define NTHR   896          // NRG*TILE_C/RPT... = 14*64, all active
#define HALO_R 17
#define HALO_C 16

__device__ __forceinline__ float clampf(float x, float lo, float hi) {
    return fminf(fmaxf(x, lo), hi);
}

// State float4 {mu, sigma, rou0(down-edge), rou1(right-edge)}.
// c1 = {2*uw1, uw2*y, ew0, ew1}.
__global__ __launch_bounds__(NTHR, 3) void tile_kernel(
    const float4* __restrict__ stI, const float4* __restrict__ vI,
    float4* __restrict__ stO, float4* __restrict__ vO,
    const float4* __restrict__ c1,
    float* __restrict__ mu_out,   // non-null on last launch (st/v not stored)
    int Tl,                       // iterations this launch (<= 16)
    int first)                    // launch 0: v := 0, vI not read
{
    __shared__ float4 buf[2][TILE_R*TS];   // 145.6 KB

    int tid = threadIdx.x;
    int rg  = tid >> 6;            // wave index == rowgroup index
    int col = tid & 63;
    int bz = blockIdx.z;
    int h0 = blockIdx.y * 32;
    int w0 = blockIdx.x * 32;
    int w  = (w0 + col - HALO_C) & 255;
    int r0 = RPT*rg;

    float4 st[RPT], v[RPT], k1[RPT];
    float2 k2[RPT];
    int hh[RPT];

    // ---- load tile: st -> LDS buf0 + regs; c1 -> regs; ew pair -> buf1 ----
    float2* ews = (float2*)&buf[1][0];   // staging view, overwritten by iter 0
#pragma unroll
    for (int k = 0; k < RPT; ++k) {
        int r = r0 + k;
        int h = (h0 + r - HALO_R) & 255;
        hh[k] = h;
        int g = (bz << 16) | (h << 8) | w;
        float4 s = stI[g];
        st[k] = s;
        buf[0][r*TS + col] = s;
        float4 K = c1[g];
        k1[k] = K;
        ews[r*TS + col] = make_float2(K.z, K.w);   // {ew0, ew1}
        v[k] = first ? make_float4(0.f, 0.f, 0.f, 0.f) : vI[g];
    }
    __syncthreads();

    // gather neighbor ew: k2 = {ew0 of up-nb, ew1 of left-nb}. Up-nb ew0 for
    // k>0 is k1[k-1].z (register); only k=0 needs the LDS staging plane.
    // Clamped at tile edge -> finite garbage; edge px are garbage-region.
    int cl = (col == 0)          ? 0          : col-1;
    int cr = (col == TILE_C-1)   ? TILE_C-1   : col+1;
    {
        int ru = (r0 == 0) ? 0 : r0-1;
        k2[0] = make_float2(ews[ru*TS + col].x, ews[r0*TS + cl].y);
#pragma unroll
        for (int k = 1; k < RPT; ++k) {
            int r = r0 + k;
            k2[k] = make_float2(k1[k-1].z, ews[r*TS + cl].y);
        }
    }
    __syncthreads();   // k2 reads done before iter-0 writes buf1

    // ---- Tl fused Jacobi iterations, one barrier each, shrinking gate ----
    for (int s = 0; s < Tl; ++s) {
        const float4* __restrict__ cur = buf[s & 1];
        float4*       __restrict__ nxt = buf[(s & 1) ^ 1];
        int rgLo = (18 - Tl + s) / RPT;   // useful rows [18-Tl+s, 47+Tl-s]
        int rgHi = (47 + Tl - s) / RPT;
        if (rg >= rgLo && rg <= rgHi) {   // wave-uniform: rg == wave id
            float4 ns[RPT];
            float4 up0 = cur[((rg == 0)     ? 0          : (r0-1))*TS + col];
            float4 dnL = cur[((rg == NRG-1) ? (TILE_R-1) : (r0+RPT))*TS + col];
#pragma unroll
            for (int k = 0; k < RPT; ++k) {
                int r = r0 + k;
                float4 lf = cur[r*TS + cl];
                float4 rt = cur[r*TS + cr];
                float4 up = (k == 0)     ? up0 : st[k-1];
                float4 dn = (k == RPT-1) ? dnL : st[k+1];
                float4 S  = st[k];
                float4 K  = k1[k];
                float2 K2 = k2[k];
                float dmu = K.x*S.x + K.y + K.z*dn.x + K.w*rt.x
                          + K2.x*up.x + K2.y*lf.x;
                float dsg = K.x*S.y + K.z*S.z*dn.y + K.w*S.w*rt.y
                          + K2.x*up.z*up.y + K2.y*lf.w*lf.y;
                float dr0 = K.z*S.y*dn.y;
                float dr1 = K.w*S.y*rt.y;
                float4 V = v[k];
                V.x = 0.7f*V.x + 0.01f*dmu;
                V.y = 0.7f*V.y + 0.01f*dsg;
                V.z = 0.7f*V.z + 0.01f*dr0;
                V.w = 0.7f*V.w + 0.01f*dr1;
                v[k] = V;
                float4 o;
                o.x = clampf(S.x + V.x, 0.f, 63.f);
                o.y = clampf(S.y + V.y, 0.001f, 50.f);
                o.z = clampf(S.z + V.z, -0.99f, 0.99f);
                o.w = clampf(S.w + V.w, -0.99f, 0.99f);
                ns[k] = o;
            }
#pragma unroll
            for (int k = 0; k < RPT; ++k) {
                st[k] = ns[k];
                nxt[(r0 + k)*TS + col] = ns[k];
            }
        }
        __syncthreads();   // all reads of cur done AND nxt fully written
    }

    // ---- store interior (rows [HALO_R, HALO_R+32), cols [HALO_C, +32)) ----
    if (col >= HALO_C && col < HALO_C+32) {
#pragma unroll
        for (int k = 0; k < RPT; ++k) {
            int r = r0 + k;
            if (r >= HALO_R && r < HALO_R+32) {
                int g = (bz << 16) | (hh[k] << 8) | w;
                if (mu_out) {
                    mu_out[g] = st[k].x;     // final launch: only mu needed
                } else {
                    stO[g] = st[k];
                    vO[g]  = v[k];
                }
            }
        }
    }
}

// ---- global max(edge_weight); gmax pre-zeroed via hipMemsetAsync ----
// (0u is the order-preserving encoding of the most-negative float)
__global__ void reduce_max_kernel(const float* __restrict__ ew, unsigned int* gmax) {
    int i = blockIdx.x*blockDim.x + threadIdx.x;
    float m = -INFINITY;
    for (; i < NEDGE; i += gridDim.x*blockDim.x) m = fmaxf(m, ew[i]);
#pragma unroll
    for (int off = 32; off > 0; off >>= 1)
        m = fmaxf(m, __shfl_down(m, off, 64));
    if ((threadIdx.x & 63) == 0) {
        unsigned u = __float_as_uint(m);
        unsigned key = (u & 0x80000000u) ? ~u : (u | 0x80000000u);
        atomicMax(gmax, key);
    }
}

// init state + invariant coefficient plane (no v plane, no c2 plane)
__global__ __launch_bounds__(256) void init_state_kernel(
    const float*  __restrict__ y,
    const float2* __restrict__ ew,
    const float2* __restrict__ uw,
    const unsigned int* __restrict__ gmax_enc,
    float4* stA, float4* c1)
{
    int idx = blockIdx.x*256 + threadIdx.x;

    unsigned key = *gmax_enc;
    unsigned u = (key & 0x80000000u) ? (key ^ 0x80000000u) : ~key;
    float gmax = __uint_as_float(u);
    float inv_denom = 1.f / (gmax*1.01f + 1.f);   // one-time, IEEE div fine

    float2 e   = ew[idx];
    float2 uwv = uw[idx];
    float  yv  = y[idx];
    float4 st;
    st.x = yv;
    st.y = 1.f;
    st.z = e.x * inv_denom;
    st.w = e.y * inv_denom;
    stA[idx] = st;
    c1[idx]  = make_float4(2.f*uwv.x, uwv.y*yv, e.x, e.y);
}

extern "C" void kernel_launch(void* const* d_in, const int* in_sizes, int n_in,
                              void* d_out, int out_size, void* d_ws, size_t ws_size,
                              hipStream_t stream) {
    const float* y  = (const float*)d_in[0];
    const float* ew = (const float*)d_in[1];
    const float* uw = (const float*)d_in[2];
    float* out = (float*)d_out;
    const int N = NPIX;

    // workspace: stA, stB, vA, vB, c1 (float4 planes) + 1 uint (~21 MB)
    float4* stA = (float4*)d_ws;
    float4* stB = stA + N;
    float4* vA  = stB + N;
    float4* vB  = vA + N;
    float4* c1  = vB + N;
    unsigned int* gmax = (unsigned int*)(c1 + N);

    hipMemsetAsync(gmax, 0, sizeof(unsigned int), stream);
    hipLaunchKernelGGL(reduce_max_kernel, dim3(512), dim3(256), 0, stream, ew, gmax);
    hipLaunchKernelGGL(init_state_kernel, dim3(N/256), dim3(256), 0, stream,
                       y, (const float2*)ew, (const float2*)uw, gmax,
                       stA, c1);

    // 6 launches of 16 iters + final launch of 4 = 100
    static const int Tls[7] = {16, 16, 16, 16, 16, 16, 4};
    float4 *stI = stA, *stO = stB, *vI = vA, *vO = vB;
    for (int l = 0; l < 7; ++l) {
        float* mo = (l == 6) ? out : nullptr;
        hipLaunchKernelGGL(tile_kernel, dim3(8, 8, 4), dim3(NTHR), 0, stream,
                           stI, vI, stO, vO, c1, mo, Tls[l], (l == 0) ? 1 : 0);
        float4* t;
        t = stI; stI = stO; stO = t;
        t = vI;  vI  = vO;  vO  = t;
    }
}